// Round 1
// baseline (19519.441 us; speedup 1.0000x reference)
//
#include <hip/hip_runtime.h>
#include <math.h>
#include <stdint.h>

#define B 128
#define S 512
#define V 6000
#define E 100
#define H 256
#define G4 1024   /* 4*H */
#define T 9

/* W column split (float4 k-groups, 64 total = 256 cols per row) */
#define WREG 20            /* cols [0,80)  "pinned": forces ~160 live load results
                              = deep load pipeline (prev-session R9/R13 win) */
#define WLDS 3             /* cols [80,92) in LDS slab (48 KB) */
#define WSTR 41            /* cols [92,256) streamed k-major (656 KB/step/dir) */

/* workspace byte offsets (256-aligned) */
#define OFF_PEMB_F 0u
#define PEMB_BYTES (V*G4*4u)                    /* 24,576,000 */
#define OFF_PEMB_B (OFF_PEMB_F + PEMB_BYTES)
#define OFF_EMF    (OFF_PEMB_B + PEMB_BYTES)    /* 49,152,000 */
#define EM_BYTES   (B*S*T*4u)                   /* 2,359,296 */
#define OFF_EMB    (OFF_EMF + EM_BYTES)
#define OFF_BP     (OFF_EMB + EM_BYTES)         /* 53,870,592 */
#define BP_BYTES   ((S-1)*B*16u)                /* 1,046,528 */
#define OFF_LT     (OFF_BP + BP_BYTES)
#define OFF_PT     (OFF_LT + 512u)
/* Streamed-W (2 dirs x 41 groups x 1024 rows x 16 B = 1,343,488 B) OVERLAYS
   the BP/LT/PT region: k_prep writes it and k_lstm reads it strictly BEFORE
   k_vit/k_back write BP/LT/PT (stream-ordered). */
#define OFF_WSTREAM OFF_BP

__device__ __forceinline__ float sigf(float x) { return 1.0f / (1.0f + expf(-x)); }

/* pemb[v][g4] = bias[g4] + sum_e emb[v][e] * W_ih[g4][e],  g4 = q*H + j */
__global__ __launch_bounds__(256) void k_pemb(const float* __restrict__ emb,
                                              const float* __restrict__ wf, const float* __restrict__ bf,
                                              const float* __restrict__ wb, const float* __restrict__ bb,
                                              char* __restrict__ ws) {
    int blk = blockIdx.x;                   /* 0..749 */
    int d   = blk >= 375;
    int vb  = d ? blk - 375 : blk;
    const float* W    = d ? wb : wf;
    const float* bias = d ? bb : bf;
    float* pe = (float*)(ws + (d ? OFF_PEMB_B : OFF_PEMB_F));

    __shared__ float es[16 * E];
    for (int i = threadIdx.x; i < 16 * E; i += 256) es[i] = emb[vb * 16 * E + i];
    __syncthreads();

    int j = threadIdx.x;
    float acc[4][16];
    #pragma unroll
    for (int q = 0; q < 4; q++) {
        float bq = bias[q * H + j];
        #pragma unroll
        for (int v = 0; v < 16; v++) acc[q][v] = bq;
    }
    for (int e = 0; e < E; e++) {
        float w0 = W[(0 * H + j) * E + e];
        float w1 = W[(1 * H + j) * E + e];
        float w2 = W[(2 * H + j) * E + e];
        float w3 = W[(3 * H + j) * E + e];
        #pragma unroll
        for (int v = 0; v < 16; v++) {
            float x = es[v * E + e];
            acc[0][v] += w0 * x; acc[1][v] += w1 * x;
            acc[2][v] += w2 * x; acc[3][v] += w3 * x;
        }
    }
    for (int v = 0; v < 16; v++)
        #pragma unroll
        for (int q = 0; q < 4; q++)
            pe[(vb * 16 + v) * G4 + q * H + j] = acc[q][v];
}

/* streamed-W layout: wstr[(d*WSTR + g)*1024 + r] = {W_d[r][92+4g .. +3]}
   -> per step, lane r loads consecutive float4 (coalesced 1 KB/wave-inst) */
__global__ __launch_bounds__(256) void k_prep(const float* __restrict__ whhf,
                                              const float* __restrict__ whhb,
                                              char* __restrict__ ws) {
    int tid = blockIdx.x * 256 + threadIdx.x;   /* 2*41*1024 = 83968 */
    if (tid >= 2 * WSTR * 1024) return;
    int d   = tid >= WSTR * 1024;
    int idx = d ? tid - WSTR * 1024 : tid;
    int g = idx >> 10, r = idx & 1023;
    const float* whh = d ? whhb : whhf;
    float4* wstr = (float4*)(ws + OFF_WSTREAM);
    const float4* src = (const float4*)(whh + (size_t)r * H + 4 * (WREG + WLDS));
    wstr[((size_t)(d * WSTR + g) << 10) + r] = src[g];
}

/* R1 (this session): TWO batches per block. 128 blocks (dir d = blk>>6,
   pair p = blk&63 -> batches 2p, 2p+1) x 512 thr. Thread t owns gate rows
   t and t+512 for BOTH batches (4 accumulators). Every streamed/reloaded W
   element now feeds 8 FLOPs instead of 4 -> aggregate L2 stream demand
   halves (21.5 -> 10.75 MB/step/XCD), which was the measured 5.7us/step
   bottleneck. W split (WREG pin / WLDS slab / WSTR stream) unchanged from
   the prior session's empirical optimum. Nonlinearity+emission tail now
   uses all 512 threads (t>>8 = batch, t&255 = h-unit). */
__global__ __attribute__((amdgpu_flat_work_group_size(512, 512), amdgpu_waves_per_eu(2, 2)))
void k_lstm(const int* __restrict__ data,
            const float* __restrict__ whhf,
            const float* __restrict__ whhb,
            const float* __restrict__ mlpW,
            char* __restrict__ ws) {
    int blk = blockIdx.x;                      /* 0..127 */
    int d = blk >> 6, p = blk & 63;
    int b0 = p * 2, b1 = b0 + 1;
    const float* whh = d ? whhb : whhf;
    const float* pe  = (const float*)(ws + (d ? OFF_PEMB_B : OFF_PEMB_F));
    float* emdst = (float*)(ws + (d ? OFF_EMB : OFF_EMF));
    const float4* wstr = (const float4*)(ws + OFF_WSTREAM) + ((size_t)(d * WSTR) << 10);

    __shared__ __align__(16) float hs[2][H];   /* h_prev per batch, 2 KB */
    __shared__ float4 sW[WLDS << 10];          /* 48 KB */
    __shared__ float  gbuf[2][G4];             /* 8 KB */
    __shared__ float  red[2][T][4];
    __shared__ int    toks[2][S];              /* 4 KB */

    int t = threadIdx.x;                       /* 0..511 */
    int r0 = t, r1 = t + 512;

    const float4* wrow0 = (const float4*)(whh + (size_t)r0 * H);
    const float4* wrow1 = (const float4*)(whh + (size_t)r1 * H);
    float4 wA[WREG], wB[WREG];
    #pragma unroll
    for (int g = 0; g < WREG; g++) { wA[g] = wrow0[g]; wB[g] = wrow1[g]; }
    /* pin: consume the loads pre-loop; keeps a deep load pipeline live */
    #pragma unroll
    for (int g = 0; g < WREG; g++) {
        asm volatile("" : "+v"(wA[g].x), "+v"(wA[g].y), "+v"(wA[g].z), "+v"(wA[g].w));
        asm volatile("" : "+v"(wB[g].x), "+v"(wB[g].y), "+v"(wB[g].z), "+v"(wB[g].w));
    }
    #pragma unroll
    for (int g = 0; g < WLDS; g++) {
        sW[(g << 10) + r0] = wrow0[WREG + g];
        sW[(g << 10) + r1] = wrow1[WREG + g];
    }

    toks[0][t] = data[b0 * S + t];             /* S == 512 == blockDim */
    toks[1][t] = data[b1 * S + t];

    float mw[T];
    {
        int j = t & 255;
        #pragma unroll
        for (int tt = 0; tt < T; tt++) mw[tt] = mlpW[tt * (2 * H) + d * H + j];
    }
    if (t < 256) hs[0][t] = 0.0f; else hs[1][t - 256] = 0.0f;
    float cst = 0.0f;
    __syncthreads();

    const float4* h40p = (const float4*)&hs[0][0];
    const float4* h41p = (const float4*)&hs[1][0];
    const float4* wsp0 = wstr + r0;
    const float4* wsp1 = wstr + r1;

    float pf00, pf01, pf10, pf11;   /* pf<row><batch> */
    {
        int sp0 = d ? (S - 1) : 0;
        size_t tk0 = (size_t)toks[0][sp0];
        size_t tk1 = (size_t)toks[1][sp0];
        pf00 = pe[(tk0 << 10) + r0];
        pf10 = pe[(tk0 << 10) + r1];
        pf01 = pe[(tk1 << 10) + r0];
        pf11 = pe[(tk1 << 10) + r1];
    }

    for (int ss = 0; ss < S; ss++) {
        int sp = d ? (S - 1 - ss) : ss;
        float a00 = pf00, a01 = pf01;          /* row r0: batch0, batch1 */
        float a10 = pf10, a11 = pf11;          /* row r1: batch0, batch1 */
        if (ss + 1 < S) {
            int spn = d ? (S - 2 - ss) : (ss + 1);
            size_t tk0 = (size_t)toks[0][spn];
            size_t tk1 = (size_t)toks[1][spn];
            pf00 = pe[(tk0 << 10) + r0];
            pf10 = pe[(tk0 << 10) + r1];
            pf01 = pe[(tk1 << 10) + r0];
            pf11 = pe[(tk1 << 10) + r1];
        }

        /* "register"-W phase: cols 0..79 */
        #pragma unroll
        for (int g = 0; g < WREG; g++) {
            float4 h0 = h40p[g], h1 = h41p[g];
            float4 a = wA[g], bw = wB[g];
            a00 = fmaf(a.x, h0.x, a00);   a01 = fmaf(a.x, h1.x, a01);
            a10 = fmaf(bw.x, h0.x, a10);  a11 = fmaf(bw.x, h1.x, a11);
            a00 = fmaf(a.y, h0.y, a00);   a01 = fmaf(a.y, h1.y, a01);
            a10 = fmaf(bw.y, h0.y, a10);  a11 = fmaf(bw.y, h1.y, a11);
            a00 = fmaf(a.z, h0.z, a00);   a01 = fmaf(a.z, h1.z, a01);
            a10 = fmaf(bw.z, h0.z, a10);  a11 = fmaf(bw.z, h1.z, a11);
            a00 = fmaf(a.w, h0.w, a00);   a01 = fmaf(a.w, h1.w, a01);
            a10 = fmaf(bw.w, h0.w, a10);  a11 = fmaf(bw.w, h1.w, a11);
        }
        /* LDS-W phase: cols 80..91 */
        #pragma unroll
        for (int g = 0; g < WLDS; g++) {
            float4 w0 = sW[(g << 10) + r0];
            float4 w1 = sW[(g << 10) + r1];
            float4 h0 = h40p[WREG + g], h1 = h41p[WREG + g];
            a00 = fmaf(w0.x, h0.x, a00);  a01 = fmaf(w0.x, h1.x, a01);
            a10 = fmaf(w1.x, h0.x, a10);  a11 = fmaf(w1.x, h1.x, a11);
            a00 = fmaf(w0.y, h0.y, a00);  a01 = fmaf(w0.y, h1.y, a01);
            a10 = fmaf(w1.y, h0.y, a10);  a11 = fmaf(w1.y, h1.y, a11);
            a00 = fmaf(w0.z, h0.z, a00);  a01 = fmaf(w0.z, h1.z, a01);
            a10 = fmaf(w1.z, h0.z, a10);  a11 = fmaf(w1.z, h1.z, a11);
            a00 = fmaf(w0.w, h0.w, a00);  a01 = fmaf(w0.w, h1.w, a01);
            a10 = fmaf(w1.w, h0.w, a10);  a11 = fmaf(w1.w, h1.w, a11);
        }
        /* streamed phase: cols 92..255 (bounded pipelining via unroll 4) */
        #pragma unroll 4
        for (int g = 0; g < WSTR; g++) {
            float4 w0 = wsp0[(size_t)g << 10];
            float4 w1 = wsp1[(size_t)g << 10];
            float4 h0 = h40p[WREG + WLDS + g], h1 = h41p[WREG + WLDS + g];
            a00 = fmaf(w0.x, h0.x, a00);  a01 = fmaf(w0.x, h1.x, a01);
            a10 = fmaf(w1.x, h0.x, a10);  a11 = fmaf(w1.x, h1.x, a11);
            a00 = fmaf(w0.y, h0.y, a00);  a01 = fmaf(w0.y, h1.y, a01);
            a10 = fmaf(w1.y, h0.y, a10);  a11 = fmaf(w1.y, h1.y, a11);
            a00 = fmaf(w0.z, h0.z, a00);  a01 = fmaf(w0.z, h1.z, a01);
            a10 = fmaf(w1.z, h0.z, a10);  a11 = fmaf(w1.z, h1.z, a11);
            a00 = fmaf(w0.w, h0.w, a00);  a01 = fmaf(w0.w, h1.w, a01);
            a10 = fmaf(w1.w, h0.w, a10);  a11 = fmaf(w1.w, h1.w, a11);
        }
        gbuf[0][r0] = a00;  gbuf[1][r0] = a01;
        gbuf[0][r1] = a10;  gbuf[1][r1] = a11;
        __syncthreads();   /* B1: gates complete, hs reads done */

        {
            int bi = t >> 8, j = t & 255;
            float gi = gbuf[bi][j],         gf = gbuf[bi][H + j];
            float gg = gbuf[bi][2 * H + j], go = gbuf[bi][3 * H + j];
            float ig = sigf(gi), fg = sigf(gf), tg = tanhf(gg), og = sigf(go);
            cst = fg * cst + ig * tg;
            float hn = og * tanhf(cst);
            hs[bi][j] = hn;
            int l = t & 63, wv = (t >> 6) & 3;
            #pragma unroll
            for (int tt = 0; tt < T; tt++) {
                float v = hn * mw[tt];
                v += __shfl_xor(v, 32, 64); v += __shfl_xor(v, 16, 64);
                v += __shfl_xor(v, 8, 64);  v += __shfl_xor(v, 4, 64);
                v += __shfl_xor(v, 2, 64);  v += __shfl_xor(v, 1, 64);
                if (l == 0) red[bi][tt][wv] = v;
            }
        }
        __syncthreads();   /* B2: hs updated + red ready */
        if (t < T)
            emdst[((size_t)b0 * S + sp) * T + t] =
                red[0][t][0] + red[0][t][1] + red[0][t][2] + red[0][t][3];
        else if (t >= 64 && t < 64 + T) {
            int tt = t - 64;
            emdst[((size_t)b1 * S + sp) * T + tt] =
                red[1][tt][0] + red[1][tt][1] + red[1][tt][2] + red[1][tt][3];
        }
    }
}

/* Viterbi forward: one wave per batch, lane t = tag. Strict-> ascending scan
   matches jnp.argmax first-index tie-breaking. */
__global__ __launch_bounds__(64) void k_vit(const int* __restrict__ data,
                                            const float* __restrict__ strans,
                                            const float* __restrict__ trans,
                                            const float* __restrict__ etrans,
                                            const float* __restrict__ mlpb,
                                            float* __restrict__ out,
                                            char* __restrict__ ws) {
    int b = blockIdx.x, t = threadIdx.x;
    const float* emf = (const float*)(ws + OFF_EMF);
    const float* emb = (const float*)(ws + OFF_EMB);
    char* bp = ws + OFF_BP;
    int*  lt = (int*)(ws + OFF_LT);
    bool act = t < T;

    float trp[T];
    float mb = 0.0f;
    if (act) {
        #pragma unroll
        for (int p = 0; p < T; p++) trp[p] = trans[p * T + t];
        mb = mlpb[t];
    }
    float score = -1e30f;
    if (act) score = strans[t] + emf[(b * S) * T + t] + emb[(b * S) * T + t] + mb;

    for (int s = 1; s < S; s++) {
        float e = 0.0f;
        if (act) e = emf[(b * S + s) * T + t] + emb[(b * S + s) * T + t] + mb;
        float best = __shfl(score, 0, 64) + trp[0];
        int bpi = 0;
        #pragma unroll
        for (int p = 1; p < T; p++) {
            float cand = __shfl(score, p, 64) + trp[p];
            if (cand > best) { best = cand; bpi = p; }
        }
        int m = data[b * S + s] != 0;
        if (act) {
            score = m ? (best + e) : score;
            bp[((size_t)(s - 1) * B + b) * 16 + t] = (char)bpi;
        }
    }
    float fin = act ? score + etrans[t] : -1e30f;
    float bv = __shfl(fin, 0, 64);
    int bi = 0;
    #pragma unroll
    for (int p = 1; p < T; p++) {
        float v = __shfl(fin, p, 64);
        if (v > bv) { bv = v; bi = p; }
    }
    if (t == 0) { out[B * S + b] = bv; lt[b] = bi; }
}

/* Backtrack: thread = batch; bp row address is tag-independent -> pipelined loads */
__global__ __launch_bounds__(128) void k_back(const int* __restrict__ data, char* __restrict__ ws) {
    int b = threadIdx.x;
    const int4* bp4 = (const int4*)(ws + OFF_BP);
    const int*  lt  = (const int*)(ws + OFF_LT);
    int* pt = (int*)(ws + OFF_PT);
    int tag = lt[b];
    pt[(S - 1) * B + b] = tag;
    for (int p = S - 2; p >= 0; p--) {
        int4 r = bp4[(size_t)p * B + b];
        int m = data[b * S + p + 1] != 0;
        unsigned w = (unsigned)(tag < 8 ? (tag < 4 ? r.x : r.y) : r.z);
        int nt = (int)((w >> ((tag & 3) * 8)) & 0xff);
        tag = m ? nt : tag;
        pt[p * B + b] = tag;
    }
}

/* paths -> float output with mask zeroing */
__global__ __launch_bounds__(256) void k_fin(const int* __restrict__ data,
                                             float* __restrict__ out,
                                             const char* __restrict__ ws) {
    int tid = blockIdx.x * 256 + threadIdx.x;   /* 65536 */
    const int* pt = (const int*)(ws + OFF_PT);
    int b = tid >> 9, p = tid & 511;
    out[tid] = (data[tid] != 0) ? (float)pt[p * B + b] : 0.0f;
}

extern "C" void kernel_launch(void* const* d_in, const int* in_sizes, int n_in,
                              void* d_out, int out_size, void* d_ws, size_t ws_size,
                              hipStream_t stream) {
    const int*   data = (const int*)d_in[0];
    /* d_in[1] = mask (bool) — unused; mask == (data != 0) */
    const float* emb  = (const float*)d_in[2];
    const float* wihf = (const float*)d_in[3];
    const float* whhf = (const float*)d_in[4];
    const float* bf   = (const float*)d_in[5];
    const float* wihb = (const float*)d_in[6];
    const float* whhb = (const float*)d_in[7];
    const float* bb   = (const float*)d_in[8];
    const float* mlpW = (const float*)d_in[9];
    const float* mlpb = (const float*)d_in[10];
    const float* st   = (const float*)d_in[11];
    const float* tr   = (const float*)d_in[12];
    const float* et   = (const float*)d_in[13];
    float* out = (float*)d_out;
    char*  ws  = (char*)d_ws;

    hipLaunchKernelGGL(k_pemb, dim3(750),  dim3(256), 0, stream, emb, wihf, bf, wihb, bb, ws);
    hipLaunchKernelGGL(k_prep, dim3(328),  dim3(256), 0, stream, whhf, whhb, ws);
    hipLaunchKernelGGL(k_lstm, dim3(128),  dim3(512), 0, stream, data, whhf, whhb, mlpW, ws);
    hipLaunchKernelGGL(k_vit,  dim3(128),  dim3(64),  0, stream, data, st, tr, et, mlpb, out, ws);
    hipLaunchKernelGGL(k_back, dim3(1),    dim3(128), 0, stream, data, ws);
    hipLaunchKernelGGL(k_fin,  dim3(256),  dim3(256), 0, stream, data, out, ws);
}

// Round 2
// 8473.717 us; speedup vs baseline: 2.3035x; 2.3035x over previous
//
#include <hip/hip_runtime.h>
#include <math.h>
#include <stdint.h>

#define B 128
#define S 512
#define V 6000
#define E 100
#define H 256
#define G4 1024   /* 4*H */
#define T 9

/* W column split (float4 k-groups, 64 total = 256 cols per row)
   R2: register-W phase REMOVED (R1 post-mortem: pinned 160-reg set spilled
   to scratch -> 12.3 GB FETCH). Groups 0..14 are re-read from whh global
   each step (row-sequential, L2-hit); 15..22 live in a 128 KB LDS slab;
   23..63 streamed k-major (layout/overlay unchanged: 4*(WGLOB+WLDS)=92). */
#define WGLOB 15           /* cols [0,60)   global re-read per step */
#define WLDS 8             /* cols [60,92)  LDS slab (128 KB) */
#define WSTR 41            /* cols [92,256) streamed k-major (656 KB/step/dir) */

/* workspace byte offsets (256-aligned) */
#define OFF_PEMB_F 0u
#define PEMB_BYTES (V*G4*4u)                    /* 24,576,000 */
#define OFF_PEMB_B (OFF_PEMB_F + PEMB_BYTES)
#define OFF_EMF    (OFF_PEMB_B + PEMB_BYTES)    /* 49,152,000 */
#define EM_BYTES   (B*S*T*4u)                   /* 2,359,296 */
#define OFF_EMB    (OFF_EMF + EM_BYTES)
#define OFF_BP     (OFF_EMB + EM_BYTES)         /* 53,870,592 */
#define BP_BYTES   ((S-1)*B*16u)                /* 1,046,528 */
#define OFF_LT     (OFF_BP + BP_BYTES)
#define OFF_PT     (OFF_LT + 512u)
/* Streamed-W (2 dirs x 41 groups x 1024 rows x 16 B = 1,343,488 B) OVERLAYS
   the BP/LT/PT region: k_prep writes it and k_lstm reads it strictly BEFORE
   k_vit/k_back write BP/LT/PT (stream-ordered). */
#define OFF_WSTREAM OFF_BP

__device__ __forceinline__ float sigf(float x) { return 1.0f / (1.0f + expf(-x)); }

/* pemb[v][g4] = bias[g4] + sum_e emb[v][e] * W_ih[g4][e],  g4 = q*H + j */
__global__ __launch_bounds__(256) void k_pemb(const float* __restrict__ emb,
                                              const float* __restrict__ wf, const float* __restrict__ bf,
                                              const float* __restrict__ wb, const float* __restrict__ bb,
                                              char* __restrict__ ws) {
    int blk = blockIdx.x;                   /* 0..749 */
    int d   = blk >= 375;
    int vb  = d ? blk - 375 : blk;
    const float* W    = d ? wb : wf;
    const float* bias = d ? bb : bf;
    float* pe = (float*)(ws + (d ? OFF_PEMB_B : OFF_PEMB_F));

    __shared__ float es[16 * E];
    for (int i = threadIdx.x; i < 16 * E; i += 256) es[i] = emb[vb * 16 * E + i];
    __syncthreads();

    int j = threadIdx.x;
    float acc[4][16];
    #pragma unroll
    for (int q = 0; q < 4; q++) {
        float bq = bias[q * H + j];
        #pragma unroll
        for (int v = 0; v < 16; v++) acc[q][v] = bq;
    }
    for (int e = 0; e < E; e++) {
        float w0 = W[(0 * H + j) * E + e];
        float w1 = W[(1 * H + j) * E + e];
        float w2 = W[(2 * H + j) * E + e];
        float w3 = W[(3 * H + j) * E + e];
        #pragma unroll
        for (int v = 0; v < 16; v++) {
            float x = es[v * E + e];
            acc[0][v] += w0 * x; acc[1][v] += w1 * x;
            acc[2][v] += w2 * x; acc[3][v] += w3 * x;
        }
    }
    for (int v = 0; v < 16; v++)
        #pragma unroll
        for (int q = 0; q < 4; q++)
            pe[(vb * 16 + v) * G4 + q * H + j] = acc[q][v];
}

/* streamed-W layout: wstr[(d*WSTR + g)*1024 + r] = {W_d[r][92+4g .. +3]}
   -> per step, lane r loads consecutive float4 (coalesced 1 KB/wave-inst) */
__global__ __launch_bounds__(256) void k_prep(const float* __restrict__ whhf,
                                              const float* __restrict__ whhb,
                                              char* __restrict__ ws) {
    int tid = blockIdx.x * 256 + threadIdx.x;   /* 2*41*1024 = 83968 */
    if (tid >= 2 * WSTR * 1024) return;
    int d   = tid >= WSTR * 1024;
    int idx = d ? tid - WSTR * 1024 : tid;
    int g = idx >> 10, r = idx & 1023;
    const float* whh = d ? whhb : whhf;
    float4* wstr = (float4*)(ws + OFF_WSTREAM);
    const float4* src = (const float4*)(whh + (size_t)r * H + 4 * (WGLOB + WLDS));
    wstr[((size_t)(d * WSTR + g) << 10) + r] = src[g];
}

/* R2 k_lstm: 128 blocks (dir d = blk>>6, pair p = blk&63 -> batches 2p,2p+1)
   x 256 thr. Thread t owns rows {t, t+256, t+512, t+768} = gates i,f,g,o of
   unit t, for BOTH batches -> nonlinearity is register-local (no gbuf), and
   one __syncthreads per step (hs double-buffered, red ping-pong).
   4 waves = 1 wave/SIMD -> VGPR budget 512, no spill possible (R1 lesson).
   Per-step per-CU model: VALU 2048 FMA/thr -> 1.7us; ds broadcasts 640 inst
   -> ~2.7us; L2 14.8 MB/step/XCD -> ~3.4us; overlapped step ~4-4.7us. */
__global__ __attribute__((amdgpu_flat_work_group_size(256, 256), amdgpu_waves_per_eu(1, 1)))
void k_lstm(const int* __restrict__ data,
            const float* __restrict__ whhf,
            const float* __restrict__ whhb,
            const float* __restrict__ mlpW,
            char* __restrict__ ws) {
    int blk = blockIdx.x;                      /* 0..127 */
    int d = blk >> 6, p = blk & 63;
    int b0 = 2 * p, b1 = b0 + 1;
    const float* whh = d ? whhb : whhf;
    const float* pe  = (const float*)(ws + (d ? OFF_PEMB_B : OFF_PEMB_F));
    float* emdst = (float*)(ws + (d ? OFF_EMB : OFF_EMF));
    const float4* wstr = (const float4*)(ws + OFF_WSTREAM) + ((size_t)(d * WSTR) << 10);

    __shared__ __align__(16) float hs[2][2][H];  /* [parity][batch][unit] 4 KB */
    __shared__ float4 sW[WLDS << 10];            /* 128 KB */
    __shared__ float  red[2][2][T][4];           /* [parity][batch][tag][wave] */
    __shared__ int    toks[2][S];                /* 4 KB */

    int t = threadIdx.x;                       /* 0..255 */

    /* per-row base pointers (rows t + 256k) */
    const float4* wr0 = (const float4*)(whh + (size_t)(t        ) * H);
    const float4* wr1 = (const float4*)(whh + (size_t)(t +  256 ) * H);
    const float4* wr2 = (const float4*)(whh + (size_t)(t +  512 ) * H);
    const float4* wr3 = (const float4*)(whh + (size_t)(t +  768 ) * H);

    /* stage LDS slab: groups WGLOB..WGLOB+WLDS-1 for all 4 owned rows */
    #pragma unroll
    for (int g = 0; g < WLDS; g++) {
        sW[(g << 10) + t       ] = wr0[WGLOB + g];
        sW[(g << 10) + t +  256] = wr1[WGLOB + g];
        sW[(g << 10) + t +  512] = wr2[WGLOB + g];
        sW[(g << 10) + t +  768] = wr3[WGLOB + g];
    }

    toks[0][t]       = data[b0 * S + t];
    toks[0][t + 256] = data[b0 * S + t + 256];
    toks[1][t]       = data[b1 * S + t];
    toks[1][t + 256] = data[b1 * S + t + 256];

    float mw[T];
    #pragma unroll
    for (int tt = 0; tt < T; tt++) mw[tt] = mlpW[tt * (2 * H) + d * H + t];

    hs[0][0][t] = 0.0f;
    hs[0][1][t] = 0.0f;
    float c0 = 0.0f, c1 = 0.0f;
    __syncthreads();

    const float4* wsp = wstr + t;              /* stream base, +k<<8 per row */

    /* prefetch first step's pemb gates (8 values: 4 rows x 2 batches) */
    float pf[4][2];
    {
        int sp0 = d ? (S - 1) : 0;
        size_t tk0 = (size_t)toks[0][sp0];
        size_t tk1 = (size_t)toks[1][sp0];
        #pragma unroll
        for (int k = 0; k < 4; k++) {
            pf[k][0] = pe[(tk0 << 10) + t + (k << 8)];
            pf[k][1] = pe[(tk1 << 10) + t + (k << 8)];
        }
    }

    int spPrev = 0;
    for (int ss = 0; ss < S; ss++) {
        int sp = d ? (S - 1 - ss) : ss;
        int par = ss & 1;

        /* deferred emission write for previous step (red[par^1], post-barrier) */
        if (ss > 0 && t < T) {
            int pp = par ^ 1;
            emdst[((size_t)b0 * S + spPrev) * T + t] =
                red[pp][0][t][0] + red[pp][0][t][1] + red[pp][0][t][2] + red[pp][0][t][3];
            emdst[((size_t)b1 * S + spPrev) * T + t] =
                red[pp][1][t][0] + red[pp][1][t][1] + red[pp][1][t][2] + red[pp][1][t][3];
        }

        float acc[4][2];
        #pragma unroll
        for (int k = 0; k < 4; k++) { acc[k][0] = pf[k][0]; acc[k][1] = pf[k][1]; }

        if (ss + 1 < S) {
            int spn = d ? (S - 2 - ss) : (ss + 1);
            size_t tk0 = (size_t)toks[0][spn];
            size_t tk1 = (size_t)toks[1][spn];
            #pragma unroll
            for (int k = 0; k < 4; k++) {
                pf[k][0] = pe[(tk0 << 10) + t + (k << 8)];
                pf[k][1] = pe[(tk1 << 10) + t + (k << 8)];
            }
        }

        const float4* h0p = (const float4*)&hs[par][0][0];
        const float4* h1p = (const float4*)&hs[par][1][0];

        /* global-W phase: groups 0..14 (cols 0..59), re-read each step (L2) */
        #pragma unroll 5
        for (int g = 0; g < WGLOB; g++) {
            float4 h0 = h0p[g], h1 = h1p[g];
            float4 w0 = wr0[g], w1 = wr1[g], w2 = wr2[g], w3 = wr3[g];
            acc[0][0] = fmaf(w0.x, h0.x, acc[0][0]);  acc[0][1] = fmaf(w0.x, h1.x, acc[0][1]);
            acc[1][0] = fmaf(w1.x, h0.x, acc[1][0]);  acc[1][1] = fmaf(w1.x, h1.x, acc[1][1]);
            acc[2][0] = fmaf(w2.x, h0.x, acc[2][0]);  acc[2][1] = fmaf(w2.x, h1.x, acc[2][1]);
            acc[3][0] = fmaf(w3.x, h0.x, acc[3][0]);  acc[3][1] = fmaf(w3.x, h1.x, acc[3][1]);
            acc[0][0] = fmaf(w0.y, h0.y, acc[0][0]);  acc[0][1] = fmaf(w0.y, h1.y, acc[0][1]);
            acc[1][0] = fmaf(w1.y, h0.y, acc[1][0]);  acc[1][1] = fmaf(w1.y, h1.y, acc[1][1]);
            acc[2][0] = fmaf(w2.y, h0.y, acc[2][0]);  acc[2][1] = fmaf(w2.y, h1.y, acc[2][1]);
            acc[3][0] = fmaf(w3.y, h0.y, acc[3][0]);  acc[3][1] = fmaf(w3.y, h1.y, acc[3][1]);
            acc[0][0] = fmaf(w0.z, h0.z, acc[0][0]);  acc[0][1] = fmaf(w0.z, h1.z, acc[0][1]);
            acc[1][0] = fmaf(w1.z, h0.z, acc[1][0]);  acc[1][1] = fmaf(w1.z, h1.z, acc[1][1]);
            acc[2][0] = fmaf(w2.z, h0.z, acc[2][0]);  acc[2][1] = fmaf(w2.z, h1.z, acc[2][1]);
            acc[3][0] = fmaf(w3.z, h0.z, acc[3][0]);  acc[3][1] = fmaf(w3.z, h1.z, acc[3][1]);
            acc[0][0] = fmaf(w0.w, h0.w, acc[0][0]);  acc[0][1] = fmaf(w0.w, h1.w, acc[0][1]);
            acc[1][0] = fmaf(w1.w, h0.w, acc[1][0]);  acc[1][1] = fmaf(w1.w, h1.w, acc[1][1]);
            acc[2][0] = fmaf(w2.w, h0.w, acc[2][0]);  acc[2][1] = fmaf(w2.w, h1.w, acc[2][1]);
            acc[3][0] = fmaf(w3.w, h0.w, acc[3][0]);  acc[3][1] = fmaf(w3.w, h1.w, acc[3][1]);
        }
        /* LDS-W phase: groups 15..22 (cols 60..91) */
        #pragma unroll
        for (int g = 0; g < WLDS; g++) {
            float4 h0 = h0p[WGLOB + g], h1 = h1p[WGLOB + g];
            float4 w0 = sW[(g << 10) + t       ];
            float4 w1 = sW[(g << 10) + t +  256];
            float4 w2 = sW[(g << 10) + t +  512];
            float4 w3 = sW[(g << 10) + t +  768];
            acc[0][0] = fmaf(w0.x, h0.x, acc[0][0]);  acc[0][1] = fmaf(w0.x, h1.x, acc[0][1]);
            acc[1][0] = fmaf(w1.x, h0.x, acc[1][0]);  acc[1][1] = fmaf(w1.x, h1.x, acc[1][1]);
            acc[2][0] = fmaf(w2.x, h0.x, acc[2][0]);  acc[2][1] = fmaf(w2.x, h1.x, acc[2][1]);
            acc[3][0] = fmaf(w3.x, h0.x, acc[3][0]);  acc[3][1] = fmaf(w3.x, h1.x, acc[3][1]);
            acc[0][0] = fmaf(w0.y, h0.y, acc[0][0]);  acc[0][1] = fmaf(w0.y, h1.y, acc[0][1]);
            acc[1][0] = fmaf(w1.y, h0.y, acc[1][0]);  acc[1][1] = fmaf(w1.y, h1.y, acc[1][1]);
            acc[2][0] = fmaf(w2.y, h0.y, acc[2][0]);  acc[2][1] = fmaf(w2.y, h1.y, acc[2][1]);
            acc[3][0] = fmaf(w3.y, h0.y, acc[3][0]);  acc[3][1] = fmaf(w3.y, h1.y, acc[3][1]);
            acc[0][0] = fmaf(w0.z, h0.z, acc[0][0]);  acc[0][1] = fmaf(w0.z, h1.z, acc[0][1]);
            acc[1][0] = fmaf(w1.z, h0.z, acc[1][0]);  acc[1][1] = fmaf(w1.z, h1.z, acc[1][1]);
            acc[2][0] = fmaf(w2.z, h0.z, acc[2][0]);  acc[2][1] = fmaf(w2.z, h1.z, acc[2][1]);
            acc[3][0] = fmaf(w3.z, h0.z, acc[3][0]);  acc[3][1] = fmaf(w3.z, h1.z, acc[3][1]);
            acc[0][0] = fmaf(w0.w, h0.w, acc[0][0]);  acc[0][1] = fmaf(w0.w, h1.w, acc[0][1]);
            acc[1][0] = fmaf(w1.w, h0.w, acc[1][0]);  acc[1][1] = fmaf(w1.w, h1.w, acc[1][1]);
            acc[2][0] = fmaf(w2.w, h0.w, acc[2][0]);  acc[2][1] = fmaf(w2.w, h1.w, acc[2][1]);
            acc[3][0] = fmaf(w3.w, h0.w, acc[3][0]);  acc[3][1] = fmaf(w3.w, h1.w, acc[3][1]);
        }
        /* streamed phase: groups 23..63 (cols 92..255), coalesced from L2 */
        #pragma unroll 8
        for (int g = 0; g < WSTR; g++) {
            float4 h0 = h0p[WGLOB + WLDS + g], h1 = h1p[WGLOB + WLDS + g];
            const float4* wg = wsp + ((size_t)g << 10);
            float4 w0 = wg[0], w1 = wg[256], w2 = wg[512], w3 = wg[768];
            acc[0][0] = fmaf(w0.x, h0.x, acc[0][0]);  acc[0][1] = fmaf(w0.x, h1.x, acc[0][1]);
            acc[1][0] = fmaf(w1.x, h0.x, acc[1][0]);  acc[1][1] = fmaf(w1.x, h1.x, acc[1][1]);
            acc[2][0] = fmaf(w2.x, h0.x, acc[2][0]);  acc[2][1] = fmaf(w2.x, h1.x, acc[2][1]);
            acc[3][0] = fmaf(w3.x, h0.x, acc[3][0]);  acc[3][1] = fmaf(w3.x, h1.x, acc[3][1]);
            acc[0][0] = fmaf(w0.y, h0.y, acc[0][0]);  acc[0][1] = fmaf(w0.y, h1.y, acc[0][1]);
            acc[1][0] = fmaf(w1.y, h0.y, acc[1][0]);  acc[1][1] = fmaf(w1.y, h1.y, acc[1][1]);
            acc[2][0] = fmaf(w2.y, h0.y, acc[2][0]);  acc[2][1] = fmaf(w2.y, h1.y, acc[2][1]);
            acc[3][0] = fmaf(w3.y, h0.y, acc[3][0]);  acc[3][1] = fmaf(w3.y, h1.y, acc[3][1]);
            acc[0][0] = fmaf(w0.z, h0.z, acc[0][0]);  acc[0][1] = fmaf(w0.z, h1.z, acc[0][1]);
            acc[1][0] = fmaf(w1.z, h0.z, acc[1][0]);  acc[1][1] = fmaf(w1.z, h1.z, acc[1][1]);
            acc[2][0] = fmaf(w2.z, h0.z, acc[2][0]);  acc[2][1] = fmaf(w2.z, h1.z, acc[2][1]);
            acc[3][0] = fmaf(w3.z, h0.z, acc[3][0]);  acc[3][1] = fmaf(w3.z, h1.z, acc[3][1]);
            acc[0][0] = fmaf(w0.w, h0.w, acc[0][0]);  acc[0][1] = fmaf(w0.w, h1.w, acc[0][1]);
            acc[1][0] = fmaf(w1.w, h0.w, acc[1][0]);  acc[1][1] = fmaf(w1.w, h1.w, acc[1][1]);
            acc[2][0] = fmaf(w2.w, h0.w, acc[2][0]);  acc[2][1] = fmaf(w2.w, h1.w, acc[2][1]);
            acc[3][0] = fmaf(w3.w, h0.w, acc[3][0]);  acc[3][1] = fmaf(w3.w, h1.w, acc[3][1]);
        }

        /* tail: thread t holds gates i,f,g,o of unit t for both batches */
        int nxt = par ^ 1;
        float hn0, hn1;
        {
            float ig = sigf(acc[0][0]), fg = sigf(acc[1][0]);
            float tg = tanhf(acc[2][0]), og = sigf(acc[3][0]);
            c0 = fg * c0 + ig * tg;
            hn0 = og * tanhf(c0);
            hs[nxt][0][t] = hn0;
        }
        {
            float ig = sigf(acc[0][1]), fg = sigf(acc[1][1]);
            float tg = tanhf(acc[2][1]), og = sigf(acc[3][1]);
            c1 = fg * c1 + ig * tg;
            hn1 = og * tanhf(c1);
            hs[nxt][1][t] = hn1;
        }
        int l = t & 63, wv = t >> 6;
        #pragma unroll
        for (int tt = 0; tt < T; tt++) {
            float v0 = hn0 * mw[tt];
            float v1 = hn1 * mw[tt];
            v0 += __shfl_xor(v0, 32, 64);  v1 += __shfl_xor(v1, 32, 64);
            v0 += __shfl_xor(v0, 16, 64);  v1 += __shfl_xor(v1, 16, 64);
            v0 += __shfl_xor(v0, 8, 64);   v1 += __shfl_xor(v1, 8, 64);
            v0 += __shfl_xor(v0, 4, 64);   v1 += __shfl_xor(v1, 4, 64);
            v0 += __shfl_xor(v0, 2, 64);   v1 += __shfl_xor(v1, 2, 64);
            v0 += __shfl_xor(v0, 1, 64);   v1 += __shfl_xor(v1, 1, 64);
            if (l == 0) { red[par][0][tt][wv] = v0; red[par][1][tt][wv] = v1; }
        }
        spPrev = sp;
        __syncthreads();   /* the ONLY barrier per step */
    }
    /* flush last step's emissions */
    if (t < T) {
        int pp = (S - 1) & 1;
        emdst[((size_t)b0 * S + spPrev) * T + t] =
            red[pp][0][t][0] + red[pp][0][t][1] + red[pp][0][t][2] + red[pp][0][t][3];
        emdst[((size_t)b1 * S + spPrev) * T + t] =
            red[pp][1][t][0] + red[pp][1][t][1] + red[pp][1][t][2] + red[pp][1][t][3];
    }
}

/* Viterbi forward: one wave per batch, lane t = tag. Strict-> ascending scan
   matches jnp.argmax first-index tie-breaking. */
__global__ __launch_bounds__(64) void k_vit(const int* __restrict__ data,
                                            const float* __restrict__ strans,
                                            const float* __restrict__ trans,
                                            const float* __restrict__ etrans,
                                            const float* __restrict__ mlpb,
                                            float* __restrict__ out,
                                            char* __restrict__ ws) {
    int b = blockIdx.x, t = threadIdx.x;
    const float* emf = (const float*)(ws + OFF_EMF);
    const float* emb = (const float*)(ws + OFF_EMB);
    char* bp = ws + OFF_BP;
    int*  lt = (int*)(ws + OFF_LT);
    bool act = t < T;

    float trp[T];
    float mb = 0.0f;
    if (act) {
        #pragma unroll
        for (int p = 0; p < T; p++) trp[p] = trans[p * T + t];
        mb = mlpb[t];
    }
    float score = -1e30f;
    if (act) score = strans[t] + emf[(b * S) * T + t] + emb[(b * S) * T + t] + mb;

    for (int s = 1; s < S; s++) {
        float e = 0.0f;
        if (act) e = emf[(b * S + s) * T + t] + emb[(b * S + s) * T + t] + mb;
        float best = __shfl(score, 0, 64) + trp[0];
        int bpi = 0;
        #pragma unroll
        for (int p = 1; p < T; p++) {
            float cand = __shfl(score, p, 64) + trp[p];
            if (cand > best) { best = cand; bpi = p; }
        }
        int m = data[b * S + s] != 0;
        if (act) {
            score = m ? (best + e) : score;
            bp[((size_t)(s - 1) * B + b) * 16 + t] = (char)bpi;
        }
    }
    float fin = act ? score + etrans[t] : -1e30f;
    float bv = __shfl(fin, 0, 64);
    int bi = 0;
    #pragma unroll
    for (int p = 1; p < T; p++) {
        float v = __shfl(fin, p, 64);
        if (v > bv) { bv = v; bi = p; }
    }
    if (t == 0) { out[B * S + b] = bv; lt[b] = bi; }
}

/* Backtrack: thread = batch; bp row address is tag-independent -> pipelined loads */
__global__ __launch_bounds__(128) void k_back(const int* __restrict__ data, char* __restrict__ ws) {
    int b = threadIdx.x;
    const int4* bp4 = (const int4*)(ws + OFF_BP);
    const int*  lt  = (const int*)(ws + OFF_LT);
    int* pt = (int*)(ws + OFF_PT);
    int tag = lt[b];
    pt[(S - 1) * B + b] = tag;
    for (int p = S - 2; p >= 0; p--) {
        int4 r = bp4[(size_t)p * B + b];
        int m = data[b * S + p + 1] != 0;
        unsigned w = (unsigned)(tag < 8 ? (tag < 4 ? r.x : r.y) : r.z);
        int nt = (int)((w >> ((tag & 3) * 8)) & 0xff);
        tag = m ? nt : tag;
        pt[p * B + b] = tag;
    }
}

/* paths -> float output with mask zeroing */
__global__ __launch_bounds__(256) void k_fin(const int* __restrict__ data,
                                             float* __restrict__ out,
                                             const char* __restrict__ ws) {
    int tid = blockIdx.x * 256 + threadIdx.x;   /* 65536 */
    const int* pt = (const int*)(ws + OFF_PT);
    int b = tid >> 9, p = tid & 511;
    out[tid] = (data[tid] != 0) ? (float)pt[p * B + b] : 0.0f;
}

extern "C" void kernel_launch(void* const* d_in, const int* in_sizes, int n_in,
                              void* d_out, int out_size, void* d_ws, size_t ws_size,
                              hipStream_t stream) {
    const int*   data = (const int*)d_in[0];
    /* d_in[1] = mask (bool) — unused; mask == (data != 0) */
    const float* emb  = (const float*)d_in[2];
    const float* wihf = (const float*)d_in[3];
    const float* whhf = (const float*)d_in[4];
    const float* bf   = (const float*)d_in[5];
    const float* wihb = (const float*)d_in[6];
    const float* whhb = (const float*)d_in[7];
    const float* bb   = (const float*)d_in[8];
    const float* mlpW = (const float*)d_in[9];
    const float* mlpb = (const float*)d_in[10];
    const float* st   = (const float*)d_in[11];
    const float* tr   = (const float*)d_in[12];
    const float* et   = (const float*)d_in[13];
    float* out = (float*)d_out;
    char*  ws  = (char*)d_ws;

    hipLaunchKernelGGL(k_pemb, dim3(750),  dim3(256), 0, stream, emb, wihf, bf, wihb, bb, ws);
    hipLaunchKernelGGL(k_prep, dim3(328),  dim3(256), 0, stream, whhf, whhb, ws);
    hipLaunchKernelGGL(k_lstm, dim3(128),  dim3(256), 0, stream, data, whhf, whhb, mlpW, ws);
    hipLaunchKernelGGL(k_vit,  dim3(128),  dim3(64),  0, stream, data, st, tr, et, mlpb, out, ws);
    hipLaunchKernelGGL(k_back, dim3(1),    dim3(128), 0, stream, data, ws);
    hipLaunchKernelGGL(k_fin,  dim3(256),  dim3(256), 0, stream, data, out, ws);
}